// Round 1
// baseline (761.287 us; speedup 1.0000x reference)
//
#include <hip/hip_runtime.h>
#include <math.h>

#define N_NODES 50000
#define E_EDGES 500000
#define E_TOT   550000     // edges + self loops
#define IN_DIM  128
#define HID     64
#define HEADS   8
#define HC      512        // HEADS*HID
#define OUT_DIM 40
#define NEG_SLOPE 0.2f

__device__ __forceinline__ float leaky(float v){ return v > 0.f ? v : NEG_SLOPE * v; }

// ---------------- sort edges by dst (counting sort -> CSR) ----------------

__global__ void k_hist(const int* __restrict__ ei, int* __restrict__ counts){
    int i = blockIdx.x * 256 + threadIdx.x;
    if (i < E_EDGES){
        atomicAdd(&counts[ei[E_EDGES + i]], 1);      // dst row of edge_index
    } else if (i < E_TOT){
        atomicAdd(&counts[i - E_EDGES], 1);          // self loop dst=i
    }
}

__global__ void k_scanA(const int* __restrict__ counts, int* __restrict__ offsets,
                        int* __restrict__ blockSums){
    __shared__ int sh[1024];
    int b = blockIdx.x, t = threadIdx.x;
    int i = b * 1024 + t;
    int v = (i < N_NODES) ? counts[i] : 0;
    sh[t] = v; __syncthreads();
    for (int off = 1; off < 1024; off <<= 1){
        int add = (t >= off) ? sh[t - off] : 0;
        __syncthreads();
        sh[t] += add;
        __syncthreads();
    }
    if (i < N_NODES) offsets[i + 1] = sh[t];
    if (t == 1023) blockSums[b] = sh[t];
}

__global__ void k_scanB(int* __restrict__ blockSums, int nb){
    if (threadIdx.x == 0 && blockIdx.x == 0){
        int run = 0;
        for (int b = 0; b < nb; b++){ int v = blockSums[b]; blockSums[b] = run; run += v; }
    }
}

__global__ void k_scanC(const int* __restrict__ counts, int* __restrict__ offsets,
                        const int* __restrict__ blockSums, int* __restrict__ cursor){
    int b = blockIdx.x, t = threadIdx.x;
    int i = b * 1024 + t;
    if (i < N_NODES){
        int v = offsets[i + 1] + blockSums[b];
        offsets[i + 1] = v;
        cursor[i] = v - counts[i];
    }
    if (i == 0) offsets[0] = 0;
}

__global__ void k_scatter(const int* __restrict__ ei, int* __restrict__ cursor,
                          int* __restrict__ sortedSrc){
    int i = blockIdx.x * 256 + threadIdx.x;
    if (i < E_EDGES){
        int d = ei[E_EDGES + i];
        int pos = atomicAdd(&cursor[d], 1);
        sortedSrc[pos] = ei[i];
    } else if (i < E_TOT){
        int n = i - E_EDGES;
        int pos = atomicAdd(&cursor[n], 1);
        sortedSrc[pos] = n;
    }
}

// ---------------- layer 1 ----------------

// x[50000,128] @ W1[128,512] -> h1[50000,512]; 16-row tile, x in LDS.
__global__ __launch_bounds__(256) void k_gemm1(const float* __restrict__ x,
                                               const float* __restrict__ W1,
                                               float* __restrict__ h1){
    __shared__ float xs[16][IN_DIM];
    int t = threadIdx.x;
    int row0 = blockIdx.x * 16;
    for (int i = t; i < 16 * IN_DIM; i += 256){
        int r = i >> 7, k = i & 127;
        xs[r][k] = x[(size_t)(row0 + r) * IN_DIM + k];
    }
    __syncthreads();
    int j0 = t, j1 = t + 256;
    float acc0[16], acc1[16];
    #pragma unroll
    for (int r = 0; r < 16; r++){ acc0[r] = 0.f; acc1[r] = 0.f; }
    for (int k = 0; k < IN_DIM; k++){
        float w0 = W1[k * HC + j0];
        float w1 = W1[k * HC + j1];
        #pragma unroll
        for (int r = 0; r < 16; r++){
            float xv = xs[r][k];
            acc0[r] = fmaf(xv, w0, acc0[r]);
            acc1[r] = fmaf(xv, w1, acc1[r]);
        }
    }
    for (int r = 0; r < 16; r++){
        h1[(size_t)(row0 + r) * HC + j0] = acc0[r];
        h1[(size_t)(row0 + r) * HC + j1] = acc1[r];
    }
}

// per-node attention dot products: e1s[n,h] = sum_c h1[n,h,c]*a1_src[h,c]
__global__ __launch_bounds__(256) void k_e1(const float* __restrict__ h1,
                                            const float* __restrict__ a1s,
                                            const float* __restrict__ a1d,
                                            float* __restrict__ e1s, float* __restrict__ e1d){
    int wave = threadIdx.x >> 6, lane = threadIdx.x & 63;
    int n = blockIdx.x * 4 + wave;
    if (n >= N_NODES) return;
    float ps[HEADS], pd[HEADS];
    #pragma unroll
    for (int h = 0; h < HEADS; h++){
        float v = h1[(size_t)n * HC + h * 64 + lane];
        ps[h] = v * a1s[h * 64 + lane];
        pd[h] = v * a1d[h * 64 + lane];
    }
    #pragma unroll
    for (int off = 32; off > 0; off >>= 1){
        #pragma unroll
        for (int h = 0; h < HEADS; h++){
            ps[h] += __shfl_xor(ps[h], off, 64);
            pd[h] += __shfl_xor(pd[h], off, 64);
        }
    }
    if (lane == 0){
        #pragma unroll
        for (int h = 0; h < HEADS; h++){
            e1s[n * HEADS + h] = ps[h];
            e1d[n * HEADS + h] = pd[h];
        }
    }
}

// segment softmax + weighted aggregation, layer 1. One block per dst node.
__global__ __launch_bounds__(256) void k_agg1(const float* __restrict__ h1,
                                              const float* __restrict__ e1s,
                                              const float* __restrict__ e1d,
                                              const int* __restrict__ offsets,
                                              const int* __restrict__ sortedSrc,
                                              const float* __restrict__ b1,
                                              float* __restrict__ hmid){
    int d = blockIdx.x;
    int beg = offsets[d], end = offsets[d + 1];
    __shared__ float m[HEADS];
    int t = threadIdx.x;
    if (t < 64){
        float mx[HEADS];
        #pragma unroll
        for (int h = 0; h < HEADS; h++) mx[h] = -INFINITY;
        float ed[HEADS];
        #pragma unroll
        for (int h = 0; h < HEADS; h++) ed[h] = e1d[d * HEADS + h];
        for (int e = beg + t; e < end; e += 64){
            int s = sortedSrc[e];
            #pragma unroll
            for (int h = 0; h < HEADS; h++){
                float v = leaky(e1s[s * HEADS + h] + ed[h]);
                mx[h] = fmaxf(mx[h], v);
            }
        }
        #pragma unroll
        for (int off = 32; off > 0; off >>= 1){
            #pragma unroll
            for (int h = 0; h < HEADS; h++) mx[h] = fmaxf(mx[h], __shfl_xor(mx[h], off, 64));
        }
        if (t < HEADS) m[t] = mx[t];
    }
    __syncthreads();
    int c0 = t, c1 = t + 256;
    int h0 = c0 >> 6, h1i = c1 >> 6;
    float ed0 = e1d[d * HEADS + h0], ed1 = e1d[d * HEADS + h1i];
    float m0 = m[h0], m1 = m[h1i];
    float acc0 = 0.f, acc1 = 0.f, z0 = 0.f, z1 = 0.f;
    for (int e = beg; e < end; e++){
        int s = sortedSrc[e];
        float l0 = leaky(e1s[s * HEADS + h0] + ed0);
        float l1 = leaky(e1s[s * HEADS + h1i] + ed1);
        float w0 = expf(l0 - m0), w1 = expf(l1 - m1);
        z0 += w0; z1 += w1;
        const float* hp = h1 + (size_t)s * HC;
        acc0 = fmaf(w0, hp[c0], acc0);
        acc1 = fmaf(w1, hp[c1], acc1);
    }
    float o0 = acc0 / (z0 + 1e-16f) + b1[c0]; o0 = fmaxf(o0, 0.f);
    float o1 = acc1 / (z1 + 1e-16f) + b1[c1]; o1 = fmaxf(o1, 0.f);
    hmid[(size_t)d * HC + c0] = o0;
    hmid[(size_t)d * HC + c1] = o1;
}

// ---------------- layer 2 ----------------

// hmid[50000,512] @ W2[512,40] -> h2[50000,40]; 64-row tile.
__global__ __launch_bounds__(256) void k_gemm2(const float* __restrict__ hmid,
                                               const float* __restrict__ W2,
                                               float* __restrict__ h2){
    __shared__ float hs[64][64];
    __shared__ float ws[64 * OUT_DIM];
    int t = threadIdx.x;
    int row0 = blockIdx.x * 64;
    int col = t & 63;
    int rbase = t >> 6;           // 0..3
    float acc[16];
    #pragma unroll
    for (int i = 0; i < 16; i++) acc[i] = 0.f;
    for (int kb = 0; kb < HC; kb += 64){
        for (int i = t; i < 64 * 64; i += 256){
            int r = i >> 6, k = i & 63;
            int gr = row0 + r;
            hs[r][k] = (gr < N_NODES) ? hmid[(size_t)gr * HC + kb + k] : 0.f;
        }
        for (int i = t; i < 64 * OUT_DIM; i += 256){
            int k = i / OUT_DIM, j = i % OUT_DIM;
            ws[i] = W2[(size_t)(kb + k) * OUT_DIM + j];
        }
        __syncthreads();
        if (col < OUT_DIM){
            for (int k = 0; k < 64; k++){
                float w = ws[k * OUT_DIM + col];
                #pragma unroll
                for (int i = 0; i < 16; i++)
                    acc[i] = fmaf(hs[rbase + 4 * i][k], w, acc[i]);
            }
        }
        __syncthreads();
    }
    if (col < OUT_DIM){
        #pragma unroll
        for (int i = 0; i < 16; i++){
            int gr = row0 + rbase + 4 * i;
            if (gr < N_NODES) h2[(size_t)gr * OUT_DIM + col] = acc[i];
        }
    }
}

__global__ __launch_bounds__(256) void k_e2(const float* __restrict__ h2,
                                            const float* __restrict__ a2s,
                                            const float* __restrict__ a2d,
                                            float* __restrict__ e2s, float* __restrict__ e2d){
    int wave = threadIdx.x >> 6, lane = threadIdx.x & 63;
    int n = blockIdx.x * 4 + wave;
    if (n >= N_NODES) return;
    float vs = 0.f, vd = 0.f;
    if (lane < OUT_DIM){
        float v = h2[(size_t)n * OUT_DIM + lane];
        vs = v * a2s[lane];
        vd = v * a2d[lane];
    }
    #pragma unroll
    for (int off = 32; off > 0; off >>= 1){
        vs += __shfl_xor(vs, off, 64);
        vd += __shfl_xor(vd, off, 64);
    }
    if (lane == 0){ e2s[n] = vs; e2d[n] = vd; }
}

// layer-2 aggregation + bias + log_softmax -> final output. One wave per node.
__global__ __launch_bounds__(64) void k_agg2(const float* __restrict__ h2,
                                             const float* __restrict__ e2s,
                                             const float* __restrict__ e2d,
                                             const int* __restrict__ offsets,
                                             const int* __restrict__ sortedSrc,
                                             const float* __restrict__ b2,
                                             float* __restrict__ out){
    int d = blockIdx.x;
    int lane = threadIdx.x;
    int beg = offsets[d], end = offsets[d + 1];
    float ed = e2d[d];
    float mx = -INFINITY;
    for (int e = beg + lane; e < end; e += 64){
        int s = sortedSrc[e];
        mx = fmaxf(mx, leaky(e2s[s] + ed));
    }
    #pragma unroll
    for (int off = 32; off > 0; off >>= 1) mx = fmaxf(mx, __shfl_xor(mx, off, 64));
    float acc = 0.f, z = 0.f;
    for (int e = beg; e < end; e++){
        int s = sortedSrc[e];
        float w = expf(leaky(e2s[s] + ed) - mx);
        z += w;
        if (lane < OUT_DIM) acc = fmaf(w, h2[(size_t)s * OUT_DIM + lane], acc);
    }
    float o = acc / (z + 1e-16f) + ((lane < OUT_DIM) ? b2[lane] : 0.f);
    float ov = (lane < OUT_DIM) ? o : -INFINITY;
    float vmax = ov;
    #pragma unroll
    for (int off = 32; off > 0; off >>= 1) vmax = fmaxf(vmax, __shfl_xor(vmax, off, 64));
    float se = (lane < OUT_DIM) ? expf(o - vmax) : 0.f;
    #pragma unroll
    for (int off = 32; off > 0; off >>= 1) se += __shfl_xor(se, off, 64);
    if (lane < OUT_DIM) out[(size_t)d * OUT_DIM + lane] = o - vmax - logf(se);
}

// ---------------- launch ----------------

extern "C" void kernel_launch(void* const* d_in, const int* in_sizes, int n_in,
                              void* d_out, int out_size, void* d_ws, size_t ws_size,
                              hipStream_t stream){
    const float* x   = (const float*)d_in[0];
    const int*   ei  = (const int*)  d_in[1];
    const float* W1  = (const float*)d_in[2];
    const float* a1s = (const float*)d_in[3];
    const float* a1d = (const float*)d_in[4];
    const float* b1  = (const float*)d_in[5];
    const float* W2  = (const float*)d_in[6];
    const float* a2s = (const float*)d_in[7];
    const float* a2d = (const float*)d_in[8];
    const float* b2  = (const float*)d_in[9];
    float* out = (float*)d_out;

    char* ws = (char*)d_ws;
    size_t off = 0;
    auto alloc = [&](size_t bytes) -> char* {
        off = (off + 255) & ~(size_t)255;
        char* p = ws + off;
        off += bytes;
        return p;
    };

    float* h1      = (float*)alloc((size_t)N_NODES * HC * 4);
    float* hmid    = (float*)alloc((size_t)N_NODES * HC * 4);
    float* h2      = (float*)alloc((size_t)N_NODES * OUT_DIM * 4);
    float* e1s     = (float*)alloc((size_t)N_NODES * HEADS * 4);
    float* e1d     = (float*)alloc((size_t)N_NODES * HEADS * 4);
    float* e2s     = (float*)alloc((size_t)N_NODES * 4);
    float* e2d     = (float*)alloc((size_t)N_NODES * 4);
    int* counts    = (int*)alloc((size_t)N_NODES * 4);
    int* offsets   = (int*)alloc((size_t)(N_NODES + 1) * 4);
    int* cursor    = (int*)alloc((size_t)N_NODES * 4);
    int* blockSums = (int*)alloc(64 * 4);
    int* sortedSrc = (int*)alloc((size_t)E_TOT * 4);

    const int nb = (N_NODES + 1023) / 1024;  // 49

    hipMemsetAsync(counts, 0, (size_t)N_NODES * 4, stream);
    k_hist   <<<(E_TOT + 255) / 256, 256, 0, stream>>>(ei, counts);
    k_scanA  <<<nb, 1024, 0, stream>>>(counts, offsets, blockSums);
    k_scanB  <<<1, 64, 0, stream>>>(blockSums, nb);
    k_scanC  <<<nb, 1024, 0, stream>>>(counts, offsets, blockSums, cursor);
    k_scatter<<<(E_TOT + 255) / 256, 256, 0, stream>>>(ei, cursor, sortedSrc);

    k_gemm1<<<N_NODES / 16, 256, 0, stream>>>(x, W1, h1);
    k_e1   <<<(N_NODES + 3) / 4, 256, 0, stream>>>(h1, a1s, a1d, e1s, e1d);
    k_agg1 <<<N_NODES, 256, 0, stream>>>(h1, e1s, e1d, offsets, sortedSrc, b1, hmid);

    k_gemm2<<<(N_NODES + 63) / 64, 256, 0, stream>>>(hmid, W2, h2);
    k_e2   <<<(N_NODES + 3) / 4, 256, 0, stream>>>(h2, a2s, a2d, e2s, e2d);
    k_agg2 <<<N_NODES, 64, 0, stream>>>(h2, e2s, e2d, offsets, sortedSrc, b2, out);
}

// Round 2
// 662.997 us; speedup vs baseline: 1.1483x; 1.1483x over previous
//
#include <hip/hip_runtime.h>
#include <math.h>

#define N_NODES 50000
#define E_EDGES 500000
#define E_TOT   550000     // edges + self loops
#define IN_DIM  128
#define HID     64
#define HEADS   8
#define HC      512        // HEADS*HID
#define OUT_DIM 40
#define NEG_SLOPE 0.2f

__device__ __forceinline__ float leaky(float v){ return v > 0.f ? v : NEG_SLOPE * v; }

// ---------------- sort edges by dst (counting sort -> CSR) ----------------

__global__ void k_hist(const int* __restrict__ ei, int* __restrict__ counts){
    int i = blockIdx.x * 256 + threadIdx.x;
    if (i < E_EDGES){
        atomicAdd(&counts[ei[E_EDGES + i]], 1);      // dst row of edge_index
    } else if (i < E_TOT){
        atomicAdd(&counts[i - E_EDGES], 1);          // self loop dst=i
    }
}

__global__ void k_scanA(const int* __restrict__ counts, int* __restrict__ offsets,
                        int* __restrict__ blockSums){
    __shared__ int sh[1024];
    int b = blockIdx.x, t = threadIdx.x;
    int i = b * 1024 + t;
    int v = (i < N_NODES) ? counts[i] : 0;
    sh[t] = v; __syncthreads();
    for (int off = 1; off < 1024; off <<= 1){
        int add = (t >= off) ? sh[t - off] : 0;
        __syncthreads();
        sh[t] += add;
        __syncthreads();
    }
    if (i < N_NODES) offsets[i + 1] = sh[t];
    if (t == 1023) blockSums[b] = sh[t];
}

__global__ void k_scanB(int* __restrict__ blockSums, int nb){
    if (threadIdx.x == 0 && blockIdx.x == 0){
        int run = 0;
        for (int b = 0; b < nb; b++){ int v = blockSums[b]; blockSums[b] = run; run += v; }
    }
}

__global__ void k_scanC(const int* __restrict__ counts, int* __restrict__ offsets,
                        const int* __restrict__ blockSums, int* __restrict__ cursor){
    int b = blockIdx.x, t = threadIdx.x;
    int i = b * 1024 + t;
    if (i < N_NODES){
        int v = offsets[i + 1] + blockSums[b];
        offsets[i + 1] = v;
        cursor[i] = v - counts[i];
    }
    if (i == 0) offsets[0] = 0;
}

__global__ void k_scatter(const int* __restrict__ ei, int* __restrict__ cursor,
                          int* __restrict__ sortedSrc){
    int i = blockIdx.x * 256 + threadIdx.x;
    if (i < E_EDGES){
        int d = ei[E_EDGES + i];
        int pos = atomicAdd(&cursor[d], 1);
        sortedSrc[pos] = ei[i];
    } else if (i < E_TOT){
        int n = i - E_EDGES;
        int pos = atomicAdd(&cursor[n], 1);
        sortedSrc[pos] = n;
    }
}

// ---------------- layer 1: GEMM + fused e1 dot products ----------------

// x[50000,128] @ W1[128,512] -> h1 ; also e1s[n,h], e1d[n,h].
// 16-row x 512-col tile; thread = 8 rows x 4 cols (float4), x broadcast from LDS.
__global__ __launch_bounds__(256) void k_gemm1e1(const float* __restrict__ x,
                                                 const float* __restrict__ W1,
                                                 const float* __restrict__ a1s,
                                                 const float* __restrict__ a1d,
                                                 float* __restrict__ h1,
                                                 float* __restrict__ e1s,
                                                 float* __restrict__ e1d){
    __shared__ float xs[16 * IN_DIM];
    const int t = threadIdx.x;
    const int row0 = blockIdx.x * 16;
    // stage x tile (2048 contiguous floats)
    const float4* xg = (const float4*)(x + (size_t)row0 * IN_DIM);
    float4* xsv = (float4*)xs;
    xsv[t] = xg[t];
    xsv[t + 256] = xg[t + 256];
    __syncthreads();

    const int ct = t & 127;        // col group: cols 4ct..4ct+3
    const int rg = t >> 7;         // 0/1 -> rows rg*8..rg*8+7
    float4 acc[8];
    #pragma unroll
    for (int r = 0; r < 8; r++) acc[r] = make_float4(0.f, 0.f, 0.f, 0.f);

    const float4* Wv = (const float4*)W1;   // [128][128 float4]
    for (int kb = 0; kb < IN_DIM; kb += 4){
        float4 w0 = Wv[(size_t)(kb + 0) * 128 + ct];
        float4 w1 = Wv[(size_t)(kb + 1) * 128 + ct];
        float4 w2 = Wv[(size_t)(kb + 2) * 128 + ct];
        float4 w3 = Wv[(size_t)(kb + 3) * 128 + ct];
        #pragma unroll
        for (int r = 0; r < 8; r++){
            float4 xv = *(const float4*)&xs[(rg * 8 + r) * IN_DIM + kb];
            acc[r].x = fmaf(xv.x, w0.x, acc[r].x); acc[r].y = fmaf(xv.x, w0.y, acc[r].y);
            acc[r].z = fmaf(xv.x, w0.z, acc[r].z); acc[r].w = fmaf(xv.x, w0.w, acc[r].w);
            acc[r].x = fmaf(xv.y, w1.x, acc[r].x); acc[r].y = fmaf(xv.y, w1.y, acc[r].y);
            acc[r].z = fmaf(xv.y, w1.z, acc[r].z); acc[r].w = fmaf(xv.y, w1.w, acc[r].w);
            acc[r].x = fmaf(xv.z, w2.x, acc[r].x); acc[r].y = fmaf(xv.z, w2.y, acc[r].y);
            acc[r].z = fmaf(xv.z, w2.z, acc[r].z); acc[r].w = fmaf(xv.z, w2.w, acc[r].w);
            acc[r].x = fmaf(xv.w, w3.x, acc[r].x); acc[r].y = fmaf(xv.w, w3.y, acc[r].y);
            acc[r].z = fmaf(xv.w, w3.z, acc[r].z); acc[r].w = fmaf(xv.w, w3.w, acc[r].w);
        }
    }

    // store h1 + fused per-head attention dots
    const float4 as4 = ((const float4*)a1s)[ct];
    const float4 ad4 = ((const float4*)a1d)[ct];
    float4* h1v = (float4*)h1;
    float ps[8], pd[8];
    #pragma unroll
    for (int r = 0; r < 8; r++){
        int row = row0 + rg * 8 + r;
        h1v[(size_t)row * 128 + ct] = acc[r];
        ps[r] = acc[r].x * as4.x + acc[r].y * as4.y + acc[r].z * as4.z + acc[r].w * as4.w;
        pd[r] = acc[r].x * ad4.x + acc[r].y * ad4.y + acc[r].z * ad4.z + acc[r].w * ad4.w;
    }
    // reduce within 16-lane (one head) groups
    #pragma unroll
    for (int off = 1; off < 16; off <<= 1){
        #pragma unroll
        for (int r = 0; r < 8; r++){
            ps[r] += __shfl_xor(ps[r], off, 64);
            pd[r] += __shfl_xor(pd[r], off, 64);
        }
    }
    if ((t & 15) == 0){
        int h = (ct >> 4) & 7;
        #pragma unroll
        for (int r = 0; r < 8; r++){
            int row = row0 + rg * 8 + r;
            e1s[(size_t)row * HEADS + h] = ps[r];
            e1d[(size_t)row * HEADS + h] = pd[r];
        }
    }
}

// ---------------- layer 1 aggregation (segment softmax, no max pass) ----------

// One block per dst node. Weights computed ONCE per (edge,head) by 4 threads/edge,
// staged in LDS; all 256 threads then do the float2 gather-accumulate.
__global__ __launch_bounds__(256) void k_agg1(const float* __restrict__ h1,
                                              const float* __restrict__ e1s,
                                              const float* __restrict__ e1d,
                                              const int* __restrict__ offsets,
                                              const int* __restrict__ sortedSrc,
                                              const float* __restrict__ b1,
                                              float* __restrict__ hmid){
    __shared__ int   ss[2][64];
    __shared__ float wl[2][64][8];
    __shared__ float zr[8];
    const int d = blockIdx.x;
    const int t = threadIdx.x;
    const int beg = offsets[d], end = offsets[d + 1];
    const int cnt = end - beg;
    const int nch = (cnt + 63) >> 6;
    if (t < 8) zr[t] = 0.f;

    const int jp = t & 3;          // head-pair: heads 2jp, 2jp+1
    const int el = t >> 2;         // edge slot within chunk
    const int hch = t >> 5;        // head of my channel pair (cols 2t,2t+1)
    const float2 ed2 = *(const float2*)&e1d[(size_t)d * HEADS + 2 * jp];
    float2 zacc = make_float2(0.f, 0.f);
    float2 acc  = make_float2(0.f, 0.f);

    // prologue: stage chunk 0 into buf 0
    {
        int e = beg + el;
        if (e < end){
            int s = sortedSrc[e];
            if (jp == 0) ss[0][el] = s;
            float2 es = *(const float2*)&e1s[(size_t)s * HEADS + 2 * jp];
            float wx = __expf(leaky(es.x + ed2.x));
            float wy = __expf(leaky(es.y + ed2.y));
            *(float2*)&wl[0][el][2 * jp] = make_float2(wx, wy);
            zacc.x += wx; zacc.y += wy;
        }
    }
    __syncthreads();

    for (int c = 0; c < nch; ++c){
        int pb = c & 1;
        if (c + 1 < nch){                       // stage next chunk into other buffer
            int e = beg + (c + 1) * 64 + el;
            if (e < end){
                int s = sortedSrc[e];
                if (jp == 0) ss[pb ^ 1][el] = s;
                float2 es = *(const float2*)&e1s[(size_t)s * HEADS + 2 * jp];
                float wx = __expf(leaky(es.x + ed2.x));
                float wy = __expf(leaky(es.y + ed2.y));
                *(float2*)&wl[pb ^ 1][el][2 * jp] = make_float2(wx, wy);
                zacc.x += wx; zacc.y += wy;
            }
        }
        int m = cnt - c * 64; if (m > 64) m = 64;
        for (int e = 0; e < m; ++e){
            int s = ss[pb][e];
            float wv = wl[pb][e][hch];
            float2 hv = *(const float2*)&h1[(size_t)s * HC + 2 * t];
            acc.x = fmaf(wv, hv.x, acc.x);
            acc.y = fmaf(wv, hv.y, acc.y);
        }
        __syncthreads();
    }

    atomicAdd(&zr[2 * jp],     zacc.x);
    atomicAdd(&zr[2 * jp + 1], zacc.y);
    __syncthreads();
    float inv = 1.f / (zr[hch] + 1e-16f);
    float2 bv = *(const float2*)&b1[2 * t];
    float ox = fmaxf(fmaf(acc.x, inv, bv.x), 0.f);
    float oy = fmaxf(fmaf(acc.y, inv, bv.y), 0.f);
    *(float2*)&hmid[(size_t)d * HC + 2 * t] = make_float2(ox, oy);
}

// ---------------- layer 2: GEMM + fused e2 ----------------

__global__ __launch_bounds__(256) void k_gemm2e2(const float* __restrict__ hmid,
                                                 const float* __restrict__ W2,
                                                 const float* __restrict__ a2s,
                                                 const float* __restrict__ a2d,
                                                 float* __restrict__ h2,
                                                 float* __restrict__ e2s,
                                                 float* __restrict__ e2d){
    __shared__ float hs[64][64];
    __shared__ float ws[64 * OUT_DIM];
    const int t = threadIdx.x;
    const int row0 = blockIdx.x * 64;
    const int col = t & 63;
    const int rbase = t >> 6;
    float acc[16];
    #pragma unroll
    for (int i = 0; i < 16; i++) acc[i] = 0.f;

    for (int kb = 0; kb < HC; kb += 64){
        for (int i = t; i < 64 * 64; i += 256){
            int r = i >> 6, k = i & 63;
            int gr = row0 + r;
            hs[r][k] = (gr < N_NODES) ? hmid[(size_t)gr * HC + kb + k] : 0.f;
        }
        for (int i = t; i < 64 * OUT_DIM; i += 256){
            int k = i / OUT_DIM, j = i - k * OUT_DIM;
            ws[i] = W2[(size_t)(kb + k) * OUT_DIM + j];
        }
        __syncthreads();
        if (col < OUT_DIM){
            for (int k = 0; k < 64; k++){
                float w = ws[k * OUT_DIM + col];
                #pragma unroll
                for (int i = 0; i < 16; i++)
                    acc[i] = fmaf(hs[rbase + 4 * i][k], w, acc[i]);
            }
        }
        __syncthreads();
    }

    const float as = (col < OUT_DIM) ? a2s[col] : 0.f;
    const float ad = (col < OUT_DIM) ? a2d[col] : 0.f;
    #pragma unroll
    for (int i = 0; i < 16; i++){
        int r = row0 + rbase + 4 * i;
        bool ok = (col < OUT_DIM) && (r < N_NODES);
        float v = ok ? acc[i] : 0.f;
        if (ok) h2[(size_t)r * OUT_DIM + col] = v;
        float pvs = v * as, pvd = v * ad;
        #pragma unroll
        for (int off = 32; off > 0; off >>= 1){
            pvs += __shfl_xor(pvs, off, 64);
            pvd += __shfl_xor(pvd, off, 64);
        }
        if (col == 0 && r < N_NODES){ e2s[r] = pvs; e2d[r] = pvd; }
    }
}

// layer-2 aggregation + bias + log_softmax (no segment-max pass). One wave per node.
__global__ __launch_bounds__(64) void k_agg2(const float* __restrict__ h2,
                                             const float* __restrict__ e2s,
                                             const float* __restrict__ e2d,
                                             const int* __restrict__ offsets,
                                             const int* __restrict__ sortedSrc,
                                             const float* __restrict__ b2,
                                             float* __restrict__ out){
    int d = blockIdx.x;
    int lane = threadIdx.x;
    int beg = offsets[d], end = offsets[d + 1];
    float ed = e2d[d];
    float acc = 0.f, z = 0.f;
    for (int e = beg; e < end; e++){
        int s = sortedSrc[e];
        float w = __expf(leaky(e2s[s] + ed));
        z += w;
        if (lane < OUT_DIM) acc = fmaf(w, h2[(size_t)s * OUT_DIM + lane], acc);
    }
    float o = acc / (z + 1e-16f) + ((lane < OUT_DIM) ? b2[lane] : 0.f);
    float ov = (lane < OUT_DIM) ? o : -INFINITY;
    float vmax = ov;
    #pragma unroll
    for (int off = 32; off > 0; off >>= 1) vmax = fmaxf(vmax, __shfl_xor(vmax, off, 64));
    float se = (lane < OUT_DIM) ? __expf(o - vmax) : 0.f;
    #pragma unroll
    for (int off = 32; off > 0; off >>= 1) se += __shfl_xor(se, off, 64);
    if (lane < OUT_DIM) out[(size_t)d * OUT_DIM + lane] = o - vmax - __logf(se);
}

// ---------------- launch ----------------

extern "C" void kernel_launch(void* const* d_in, const int* in_sizes, int n_in,
                              void* d_out, int out_size, void* d_ws, size_t ws_size,
                              hipStream_t stream){
    const float* x   = (const float*)d_in[0];
    const int*   ei  = (const int*)  d_in[1];
    const float* W1  = (const float*)d_in[2];
    const float* a1s = (const float*)d_in[3];
    const float* a1d = (const float*)d_in[4];
    const float* b1  = (const float*)d_in[5];
    const float* W2  = (const float*)d_in[6];
    const float* a2s = (const float*)d_in[7];
    const float* a2d = (const float*)d_in[8];
    const float* b2  = (const float*)d_in[9];
    float* out = (float*)d_out;

    char* ws = (char*)d_ws;
    size_t off = 0;
    auto alloc = [&](size_t bytes) -> char* {
        off = (off + 255) & ~(size_t)255;
        char* p = ws + off;
        off += bytes;
        return p;
    };

    float* h1      = (float*)alloc((size_t)N_NODES * HC * 4);
    float* hmid    = (float*)alloc((size_t)N_NODES * HC * 4);
    float* h2      = (float*)alloc((size_t)N_NODES * OUT_DIM * 4);
    float* e1s     = (float*)alloc((size_t)N_NODES * HEADS * 4);
    float* e1d     = (float*)alloc((size_t)N_NODES * HEADS * 4);
    float* e2s     = (float*)alloc((size_t)N_NODES * 4);
    float* e2d     = (float*)alloc((size_t)N_NODES * 4);
    int* counts    = (int*)alloc((size_t)N_NODES * 4);
    int* offsets   = (int*)alloc((size_t)(N_NODES + 1) * 4);
    int* cursor    = (int*)alloc((size_t)N_NODES * 4);
    int* blockSums = (int*)alloc(64 * 4);
    int* sortedSrc = (int*)alloc((size_t)E_TOT * 4);

    const int nb = (N_NODES + 1023) / 1024;  // 49

    hipMemsetAsync(counts, 0, (size_t)N_NODES * 4, stream);
    k_hist   <<<(E_TOT + 255) / 256, 256, 0, stream>>>(ei, counts);
    k_scanA  <<<nb, 1024, 0, stream>>>(counts, offsets, blockSums);
    k_scanB  <<<1, 64, 0, stream>>>(blockSums, nb);
    k_scanC  <<<nb, 1024, 0, stream>>>(counts, offsets, blockSums, cursor);
    k_scatter<<<(E_TOT + 255) / 256, 256, 0, stream>>>(ei, cursor, sortedSrc);

    k_gemm1e1<<<N_NODES / 16, 256, 0, stream>>>(x, W1, a1s, a1d, h1, e1s, e1d);
    k_agg1   <<<N_NODES, 256, 0, stream>>>(h1, e1s, e1d, offsets, sortedSrc, b1, hmid);

    k_gemm2e2<<<(N_NODES + 63) / 64, 256, 0, stream>>>(hmid, W2, a2s, a2d, h2, e2s, e2d);
    k_agg2   <<<N_NODES, 64, 0, stream>>>(h2, e2s, e2d, offsets, sortedSrc, b2, out);
}

// Round 4
// 644.086 us; speedup vs baseline: 1.1820x; 1.0294x over previous
//
#include <hip/hip_runtime.h>
#include <math.h>

#define N_NODES 50000
#define E_EDGES 500000
#define E_TOT   550000     // edges + self loops
#define IN_DIM  128
#define HID     64
#define HEADS   8
#define HC      512        // HEADS*HID
#define OUT_DIM 40
#define NEG_SLOPE 0.2f

__device__ __forceinline__ float leaky(float v){ return v > 0.f ? v : NEG_SLOPE * v; }

// ---------------- sort edges by dst (counting sort -> CSR) ----------------

__global__ void k_hist(const int* __restrict__ ei, int* __restrict__ counts){
    int i = blockIdx.x * 256 + threadIdx.x;
    if (i < E_EDGES){
        atomicAdd(&counts[ei[E_EDGES + i]], 1);      // dst row of edge_index
    } else if (i < E_TOT){
        atomicAdd(&counts[i - E_EDGES], 1);          // self loop dst=i
    }
}

__global__ void k_scanA(const int* __restrict__ counts, int* __restrict__ offsets,
                        int* __restrict__ blockSums){
    __shared__ int sh[1024];
    int b = blockIdx.x, t = threadIdx.x;
    int i = b * 1024 + t;
    int v = (i < N_NODES) ? counts[i] : 0;
    sh[t] = v; __syncthreads();
    for (int off = 1; off < 1024; off <<= 1){
        int add = (t >= off) ? sh[t - off] : 0;
        __syncthreads();
        sh[t] += add;
        __syncthreads();
    }
    if (i < N_NODES) offsets[i + 1] = sh[t];
    if (t == 1023) blockSums[b] = sh[t];
}

__global__ void k_scanB(int* __restrict__ blockSums, int nb){
    if (threadIdx.x == 0 && blockIdx.x == 0){
        int run = 0;
        for (int b = 0; b < nb; b++){ int v = blockSums[b]; blockSums[b] = run; run += v; }
    }
}

__global__ void k_scanC(const int* __restrict__ counts, int* __restrict__ offsets,
                        const int* __restrict__ blockSums, int* __restrict__ cursor){
    int b = blockIdx.x, t = threadIdx.x;
    int i = b * 1024 + t;
    if (i < N_NODES){
        int v = offsets[i + 1] + blockSums[b];
        offsets[i + 1] = v;
        cursor[i] = v - counts[i];
    }
    if (i == 0) offsets[0] = 0;
}

__global__ void k_scatter(const int* __restrict__ ei, int* __restrict__ cursor,
                          int* __restrict__ sortedSrc){
    int i = blockIdx.x * 256 + threadIdx.x;
    if (i < E_EDGES){
        int d = ei[E_EDGES + i];
        int pos = atomicAdd(&cursor[d], 1);
        sortedSrc[pos] = ei[i];
    } else if (i < E_TOT){
        int n = i - E_EDGES;
        int pos = atomicAdd(&cursor[n], 1);
        sortedSrc[pos] = n;
    }
}

// ---------------- layer 1: GEMM + fused e1 dot products ----------------

// x[50000,128] @ W1[128,512] -> h1 ; also e1s[n,h], e1d[n,h].
__global__ __launch_bounds__(256) void k_gemm1e1(const float* __restrict__ x,
                                                 const float* __restrict__ W1,
                                                 const float* __restrict__ a1s,
                                                 const float* __restrict__ a1d,
                                                 float* __restrict__ h1,
                                                 float* __restrict__ e1s,
                                                 float* __restrict__ e1d){
    __shared__ float xs[16 * IN_DIM];
    const int t = threadIdx.x;
    const int row0 = blockIdx.x * 16;
    const float4* xg = (const float4*)(x + (size_t)row0 * IN_DIM);
    float4* xsv = (float4*)xs;
    xsv[t] = xg[t];
    xsv[t + 256] = xg[t + 256];
    __syncthreads();

    const int ct = t & 127;        // col group: cols 4ct..4ct+3
    const int rg = t >> 7;         // 0/1 -> rows rg*8..rg*8+7
    float4 acc[8];
    #pragma unroll
    for (int r = 0; r < 8; r++) acc[r] = make_float4(0.f, 0.f, 0.f, 0.f);

    const float4* Wv = (const float4*)W1;   // [128][128 float4]
    for (int kb = 0; kb < IN_DIM; kb += 4){
        float4 w0 = Wv[(size_t)(kb + 0) * 128 + ct];
        float4 w1 = Wv[(size_t)(kb + 1) * 128 + ct];
        float4 w2 = Wv[(size_t)(kb + 2) * 128 + ct];
        float4 w3 = Wv[(size_t)(kb + 3) * 128 + ct];
        #pragma unroll
        for (int r = 0; r < 8; r++){
            float4 xv = *(const float4*)&xs[(rg * 8 + r) * IN_DIM + kb];
            acc[r].x = fmaf(xv.x, w0.x, acc[r].x); acc[r].y = fmaf(xv.x, w0.y, acc[r].y);
            acc[r].z = fmaf(xv.x, w0.z, acc[r].z); acc[r].w = fmaf(xv.x, w0.w, acc[r].w);
            acc[r].x = fmaf(xv.y, w1.x, acc[r].x); acc[r].y = fmaf(xv.y, w1.y, acc[r].y);
            acc[r].z = fmaf(xv.y, w1.z, acc[r].z); acc[r].w = fmaf(xv.y, w1.w, acc[r].w);
            acc[r].x = fmaf(xv.z, w2.x, acc[r].x); acc[r].y = fmaf(xv.z, w2.y, acc[r].y);
            acc[r].z = fmaf(xv.z, w2.z, acc[r].z); acc[r].w = fmaf(xv.z, w2.w, acc[r].w);
            acc[r].x = fmaf(xv.w, w3.x, acc[r].x); acc[r].y = fmaf(xv.w, w3.y, acc[r].y);
            acc[r].z = fmaf(xv.w, w3.z, acc[r].z); acc[r].w = fmaf(xv.w, w3.w, acc[r].w);
        }
    }

    const float4 as4 = ((const float4*)a1s)[ct];
    const float4 ad4 = ((const float4*)a1d)[ct];
    float4* h1v = (float4*)h1;
    float ps[8], pd[8];
    #pragma unroll
    for (int r = 0; r < 8; r++){
        int row = row0 + rg * 8 + r;
        h1v[(size_t)row * 128 + ct] = acc[r];
        ps[r] = acc[r].x * as4.x + acc[r].y * as4.y + acc[r].z * as4.z + acc[r].w * as4.w;
        pd[r] = acc[r].x * ad4.x + acc[r].y * ad4.y + acc[r].z * ad4.z + acc[r].w * ad4.w;
    }
    #pragma unroll
    for (int off = 1; off < 16; off <<= 1){
        #pragma unroll
        for (int r = 0; r < 8; r++){
            ps[r] += __shfl_xor(ps[r], off, 64);
            pd[r] += __shfl_xor(pd[r], off, 64);
        }
    }
    if ((t & 15) == 0){
        int h = (ct >> 4) & 7;
        #pragma unroll
        for (int r = 0; r < 8; r++){
            int row = row0 + rg * 8 + r;
            e1s[(size_t)row * HEADS + h] = ps[r];
            e1d[(size_t)row * HEADS + h] = pd[r];
        }
    }
}

// ---------------- layer 1 aggregation: one WAVE per node, no LDS, no barriers --

// lane l owns channels [8l, 8l+8) -> single head h = l>>3. Weight is lane-local.
// z accumulated redundantly per lane (identical within each 8-lane head group).
// Software pipeline: src index 2 edges ahead, weight+row loads 1 edge ahead.
__global__ __launch_bounds__(256) void k_agg1(const float* __restrict__ h1,
                                              const float* __restrict__ e1s,
                                              const float* __restrict__ e1d,
                                              const int* __restrict__ offsets,
                                              const int* __restrict__ sortedSrc,
                                              const float* __restrict__ b1,
                                              float* __restrict__ hmid){
    const int lane = threadIdx.x & 63;
    const int d = blockIdx.x * 4 + (threadIdx.x >> 6);
    if (d >= N_NODES) return;
    const int beg = offsets[d], end = offsets[d + 1];
    const int cnt = end - beg;
    const int h = lane >> 3;
    const int c0 = lane * 8;
    const float ed = e1d[(size_t)d * HEADS + h];

    float4 acc0 = make_float4(0.f,0.f,0.f,0.f), acc1 = make_float4(0.f,0.f,0.f,0.f);
    float z = 0.f;

    int s1 = 0, s2 = 0;
    float eA = 0.f; float4 hA0, hA1;
    {   // prologue: loads for edge 0, src for edge 1
        int s0 = sortedSrc[beg];
        eA = e1s[(size_t)s0 * HEADS + h];
        const float4* hp = (const float4*)(h1 + (size_t)s0 * HC + c0);
        hA0 = hp[0]; hA1 = hp[1];
        if (cnt > 1) s1 = sortedSrc[beg + 1];
    }
    for (int e = 0; e < cnt; ++e){
        if (e + 2 < cnt) s2 = sortedSrc[beg + e + 2];
        float eB = 0.f; float4 hB0, hB1;
        if (e + 1 < cnt){
            eB = e1s[(size_t)s1 * HEADS + h];
            const float4* hp = (const float4*)(h1 + (size_t)s1 * HC + c0);
            hB0 = hp[0]; hB1 = hp[1];
        }
        float w = __expf(leaky(eA + ed));
        z += w;
        acc0.x = fmaf(w, hA0.x, acc0.x); acc0.y = fmaf(w, hA0.y, acc0.y);
        acc0.z = fmaf(w, hA0.z, acc0.z); acc0.w = fmaf(w, hA0.w, acc0.w);
        acc1.x = fmaf(w, hA1.x, acc1.x); acc1.y = fmaf(w, hA1.y, acc1.y);
        acc1.z = fmaf(w, hA1.z, acc1.z); acc1.w = fmaf(w, hA1.w, acc1.w);
        eA = eB; hA0 = hB0; hA1 = hB1; s1 = s2;
    }

    const float inv = 1.f / (z + 1e-16f);
    const float4 bv0 = ((const float4*)b1)[lane * 2];
    const float4 bv1 = ((const float4*)b1)[lane * 2 + 1];
    float4 o0, o1;
    o0.x = fmaxf(fmaf(acc0.x, inv, bv0.x), 0.f);
    o0.y = fmaxf(fmaf(acc0.y, inv, bv0.y), 0.f);
    o0.z = fmaxf(fmaf(acc0.z, inv, bv0.z), 0.f);
    o0.w = fmaxf(fmaf(acc0.w, inv, bv0.w), 0.f);
    o1.x = fmaxf(fmaf(acc1.x, inv, bv1.x), 0.f);
    o1.y = fmaxf(fmaf(acc1.y, inv, bv1.y), 0.f);
    o1.z = fmaxf(fmaf(acc1.z, inv, bv1.z), 0.f);
    o1.w = fmaxf(fmaf(acc1.w, inv, bv1.w), 0.f);
    float4* op = (float4*)(hmid + (size_t)d * HC + c0);
    op[0] = o0; op[1] = o1;
}

// ---------------- layer 2: GEMM + fused e2 ----------------

__global__ __launch_bounds__(256) void k_gemm2e2(const float* __restrict__ hmid,
                                                 const float* __restrict__ W2,
                                                 const float* __restrict__ a2s,
                                                 const float* __restrict__ a2d,
                                                 float* __restrict__ h2,
                                                 float* __restrict__ e2s,
                                                 float* __restrict__ e2d){
    __shared__ float hs[64][64];
    __shared__ float ws[64 * OUT_DIM];
    const int t = threadIdx.x;
    const int row0 = blockIdx.x * 64;
    const int col = t & 63;
    const int rbase = t >> 6;
    float acc[16];
    #pragma unroll
    for (int i = 0; i < 16; i++) acc[i] = 0.f;

    for (int kb = 0; kb < HC; kb += 64){
        for (int i = t; i < 64 * 64; i += 256){
            int r = i >> 6, k = i & 63;
            int gr = row0 + r;
            hs[r][k] = (gr < N_NODES) ? hmid[(size_t)gr * HC + kb + k] : 0.f;
        }
        for (int i = t; i < 64 * OUT_DIM; i += 256){
            int k = i / OUT_DIM, j = i - k * OUT_DIM;
            ws[i] = W2[(size_t)(kb + k) * OUT_DIM + j];
        }
        __syncthreads();
        if (col < OUT_DIM){
            for (int k = 0; k < 64; k++){
                float w = ws[k * OUT_DIM + col];
                #pragma unroll
                for (int i = 0; i < 16; i++)
                    acc[i] = fmaf(hs[rbase + 4 * i][k], w, acc[i]);
            }
        }
        __syncthreads();
    }

    const float as = (col < OUT_DIM) ? a2s[col] : 0.f;
    const float ad = (col < OUT_DIM) ? a2d[col] : 0.f;
    #pragma unroll
    for (int i = 0; i < 16; i++){
        int r = row0 + rbase + 4 * i;
        bool ok = (col < OUT_DIM) && (r < N_NODES);
        float v = ok ? acc[i] : 0.f;
        if (ok) h2[(size_t)r * OUT_DIM + col] = v;
        float pvs = v * as, pvd = v * ad;
        #pragma unroll
        for (int off = 32; off > 0; off >>= 1){
            pvs += __shfl_xor(pvs, off, 64);
            pvd += __shfl_xor(pvd, off, 64);
        }
        if (col == 0 && r < N_NODES){ e2s[r] = pvs; e2d[r] = pvd; }
    }
}

// ---------------- layer 2 aggregation: one WAVE per node, pipelined ------------

__global__ __launch_bounds__(256) void k_agg2(const float* __restrict__ h2,
                                              const float* __restrict__ e2s,
                                              const float* __restrict__ e2d,
                                              const int* __restrict__ offsets,
                                              const int* __restrict__ sortedSrc,
                                              const float* __restrict__ b2,
                                              float* __restrict__ out){
    const int lane = threadIdx.x & 63;
    const int d = blockIdx.x * 4 + (threadIdx.x >> 6);
    if (d >= N_NODES) return;
    const int beg = offsets[d], end = offsets[d + 1];
    const int cnt = end - beg;
    const float ed = e2d[d];
    const bool act = (lane < OUT_DIM);

    float acc = 0.f, z = 0.f;
    int s1 = 0, s2 = 0;
    float eA = 0.f, hA = 0.f;
    {
        int s0 = sortedSrc[beg];
        eA = e2s[s0];
        if (act) hA = h2[(size_t)s0 * OUT_DIM + lane];
        if (cnt > 1) s1 = sortedSrc[beg + 1];
    }
    for (int e = 0; e < cnt; ++e){
        if (e + 2 < cnt) s2 = sortedSrc[beg + e + 2];
        float eB = 0.f, hB = 0.f;
        if (e + 1 < cnt){
            eB = e2s[s1];
            if (act) hB = h2[(size_t)s1 * OUT_DIM + lane];
        }
        float w = __expf(leaky(eA + ed));
        z += w;
        acc = fmaf(w, hA, acc);
        eA = eB; hA = hB; s1 = s2;
    }

    float o = acc / (z + 1e-16f) + (act ? b2[lane] : 0.f);
    float ov = act ? o : -INFINITY;
    float vmax = ov;
    #pragma unroll
    for (int off = 32; off > 0; off >>= 1) vmax = fmaxf(vmax, __shfl_xor(vmax, off, 64));
    float se = act ? __expf(o - vmax) : 0.f;
    #pragma unroll
    for (int off = 32; off > 0; off >>= 1) se += __shfl_xor(se, off, 64);
    if (act) out[(size_t)d * OUT_DIM + lane] = o - vmax - __logf(se);
}

// ---------------- launch ----------------

extern "C" void kernel_launch(void* const* d_in, const int* in_sizes, int n_in,
                              void* d_out, int out_size, void* d_ws, size_t ws_size,
                              hipStream_t stream){
    const float* x   = (const float*)d_in[0];
    const int*   ei  = (const int*)  d_in[1];
    const float* W1  = (const float*)d_in[2];
    const float* a1s = (const float*)d_in[3];
    const float* a1d = (const float*)d_in[4];
    const float* b1  = (const float*)d_in[5];
    const float* W2  = (const float*)d_in[6];
    const float* a2s = (const float*)d_in[7];
    const float* a2d = (const float*)d_in[8];
    const float* b2  = (const float*)d_in[9];
    float* out = (float*)d_out;

    char* ws = (char*)d_ws;
    size_t off = 0;
    auto alloc = [&](size_t bytes) -> char* {
        off = (off + 255) & ~(size_t)255;
        char* p = ws + off;
        off += bytes;
        return p;
    };

    float* h1      = (float*)alloc((size_t)N_NODES * HC * 4);
    float* hmid    = (float*)alloc((size_t)N_NODES * HC * 4);
    float* h2      = (float*)alloc((size_t)N_NODES * OUT_DIM * 4);
    float* e1s     = (float*)alloc((size_t)N_NODES * HEADS * 4);
    float* e1d     = (float*)alloc((size_t)N_NODES * HEADS * 4);
    float* e2s     = (float*)alloc((size_t)N_NODES * 4);
    float* e2d     = (float*)alloc((size_t)N_NODES * 4);
    int* counts    = (int*)alloc((size_t)N_NODES * 4);
    int* offsets   = (int*)alloc((size_t)(N_NODES + 1) * 4);
    int* cursor    = (int*)alloc((size_t)N_NODES * 4);
    int* blockSums = (int*)alloc(64 * 4);
    int* sortedSrc = (int*)alloc((size_t)E_TOT * 4);

    const int nb = (N_NODES + 1023) / 1024;  // 49

    hipMemsetAsync(counts, 0, (size_t)N_NODES * 4, stream);
    k_hist   <<<(E_TOT + 255) / 256, 256, 0, stream>>>(ei, counts);
    k_scanA  <<<nb, 1024, 0, stream>>>(counts, offsets, blockSums);
    k_scanB  <<<1, 64, 0, stream>>>(blockSums, nb);
    k_scanC  <<<nb, 1024, 0, stream>>>(counts, offsets, blockSums, cursor);
    k_scatter<<<(E_TOT + 255) / 256, 256, 0, stream>>>(ei, cursor, sortedSrc);

    k_gemm1e1<<<N_NODES / 16, 256, 0, stream>>>(x, W1, a1s, a1d, h1, e1s, e1d);
    k_agg1   <<<(N_NODES + 3) / 4, 256, 0, stream>>>(h1, e1s, e1d, offsets, sortedSrc, b1, hmid);

    k_gemm2e2<<<(N_NODES + 63) / 64, 256, 0, stream>>>(hmid, W2, a2s, a2d, h2, e2s, e2d);
    k_agg2   <<<(N_NODES + 3) / 4, 256, 0, stream>>>(h2, e2s, e2d, offsets, sortedSrc, b2, out);
}

// Round 14
// 560.293 us; speedup vs baseline: 1.3587x; 1.1496x over previous
//
#include <hip/hip_runtime.h>
#include <math.h>

#define N_NODES 50000
#define E_EDGES 500000
#define E_TOT   550000     // edges + self loops
#define IN_DIM  128
#define HID     64
#define HEADS   8
#define HC      512        // HEADS*HID
#define OUT_DIM 40
#define NEG_SLOPE 0.2f

__device__ __forceinline__ float leaky(float v){ return v > 0.f ? v : NEG_SLOPE * v; }

// ---------------- sort edges by dst (counting sort -> CSR) ----------------

__global__ void k_hist(const int* __restrict__ ei, int* __restrict__ counts){
    int i = blockIdx.x * 256 + threadIdx.x;
    if (i < E_EDGES){
        atomicAdd(&counts[ei[E_EDGES + i]], 1);      // dst row of edge_index
    } else if (i < E_TOT){
        atomicAdd(&counts[i - E_EDGES], 1);          // self loop dst=i
    }
}

__global__ void k_scanA(const int* __restrict__ counts, int* __restrict__ offsets,
                        int* __restrict__ blockSums){
    __shared__ int sh[1024];
    int b = blockIdx.x, t = threadIdx.x;
    int i = b * 1024 + t;
    int v = (i < N_NODES) ? counts[i] : 0;
    sh[t] = v; __syncthreads();
    for (int off = 1; off < 1024; off <<= 1){
        int add = (t >= off) ? sh[t - off] : 0;
        __syncthreads();
        sh[t] += add;
        __syncthreads();
    }
    if (i < N_NODES) offsets[i + 1] = sh[t];
    if (t == 1023) blockSums[b] = sh[t];
}

__global__ void k_scanB(int* __restrict__ blockSums, int nb){
    if (threadIdx.x == 0 && blockIdx.x == 0){
        int run = 0;
        for (int b = 0; b < nb; b++){ int v = blockSums[b]; blockSums[b] = run; run += v; }
    }
}

__global__ void k_scanC(const int* __restrict__ counts, int* __restrict__ offsets,
                        const int* __restrict__ blockSums, int* __restrict__ cursor){
    int b = blockIdx.x, t = threadIdx.x;
    int i = b * 1024 + t;
    if (i < N_NODES){
        int v = offsets[i + 1] + blockSums[b];
        offsets[i + 1] = v;
        cursor[i] = v - counts[i];
    }
    if (i == 0) offsets[0] = 0;
}

__global__ void k_scatter(const int* __restrict__ ei, int* __restrict__ cursor,
                          int* __restrict__ sortedSrc){
    int i = blockIdx.x * 256 + threadIdx.x;
    if (i < E_EDGES){
        int d = ei[E_EDGES + i];
        int pos = atomicAdd(&cursor[d], 1);
        sortedSrc[pos] = ei[i];
    } else if (i < E_TOT){
        int n = i - E_EDGES;
        int pos = atomicAdd(&cursor[n], 1);
        sortedSrc[pos] = n;
    }
}

// ---------------- layer 1: GEMM + fused e1 dot products ----------------

// x[50000,128] @ W1[128,512] -> h1 ; also e1s[n,h], e1d[n,h].
__global__ __launch_bounds__(256) void k_gemm1e1(const float* __restrict__ x,
                                                 const float* __restrict__ W1,
                                                 const float* __restrict__ a1s,
                                                 const float* __restrict__ a1d,
                                                 float* __restrict__ h1,
                                                 float* __restrict__ e1s,
                                                 float* __restrict__ e1d){
    __shared__ float xs[16 * IN_DIM];
    const int t = threadIdx.x;
    const int row0 = blockIdx.x * 16;
    const float4* xg = (const float4*)(x + (size_t)row0 * IN_DIM);
    float4* xsv = (float4*)xs;
    xsv[t] = xg[t];
    xsv[t + 256] = xg[t + 256];
    __syncthreads();

    const int ct = t & 127;        // col group: cols 4ct..4ct+3
    const int rg = t >> 7;         // 0/1 -> rows rg*8..rg*8+7
    float4 acc[8];
    #pragma unroll
    for (int r = 0; r < 8; r++) acc[r] = make_float4(0.f, 0.f, 0.f, 0.f);

    const float4* Wv = (const float4*)W1;   // [128][128 float4]
    for (int kb = 0; kb < IN_DIM; kb += 4){
        float4 w0 = Wv[(size_t)(kb + 0) * 128 + ct];
        float4 w1 = Wv[(size_t)(kb + 1) * 128 + ct];
        float4 w2 = Wv[(size_t)(kb + 2) * 128 + ct];
        float4 w3 = Wv[(size_t)(kb + 3) * 128 + ct];
        #pragma unroll
        for (int r = 0; r < 8; r++){
            float4 xv = *(const float4*)&xs[(rg * 8 + r) * IN_DIM + kb];
            acc[r].x = fmaf(xv.x, w0.x, acc[r].x); acc[r].y = fmaf(xv.x, w0.y, acc[r].y);
            acc[r].z = fmaf(xv.x, w0.z, acc[r].z); acc[r].w = fmaf(xv.x, w0.w, acc[r].w);
            acc[r].x = fmaf(xv.y, w1.x, acc[r].x); acc[r].y = fmaf(xv.y, w1.y, acc[r].y);
            acc[r].z = fmaf(xv.y, w1.z, acc[r].z); acc[r].w = fmaf(xv.y, w1.w, acc[r].w);
            acc[r].x = fmaf(xv.z, w2.x, acc[r].x); acc[r].y = fmaf(xv.z, w2.y, acc[r].y);
            acc[r].z = fmaf(xv.z, w2.z, acc[r].z); acc[r].w = fmaf(xv.z, w2.w, acc[r].w);
            acc[r].x = fmaf(xv.w, w3.x, acc[r].x); acc[r].y = fmaf(xv.w, w3.y, acc[r].y);
            acc[r].z = fmaf(xv.w, w3.z, acc[r].z); acc[r].w = fmaf(xv.w, w3.w, acc[r].w);
        }
    }

    const float4 as4 = ((const float4*)a1s)[ct];
    const float4 ad4 = ((const float4*)a1d)[ct];
    float4* h1v = (float4*)h1;
    float ps[8], pd[8];
    #pragma unroll
    for (int r = 0; r < 8; r++){
        int row = row0 + rg * 8 + r;
        h1v[(size_t)row * 128 + ct] = acc[r];
        ps[r] = acc[r].x * as4.x + acc[r].y * as4.y + acc[r].z * as4.z + acc[r].w * as4.w;
        pd[r] = acc[r].x * ad4.x + acc[r].y * ad4.y + acc[r].z * ad4.z + acc[r].w * ad4.w;
    }
    #pragma unroll
    for (int off = 1; off < 16; off <<= 1){
        #pragma unroll
        for (int r = 0; r < 8; r++){
            ps[r] += __shfl_xor(ps[r], off, 64);
            pd[r] += __shfl_xor(pd[r], off, 64);
        }
    }
    if ((t & 15) == 0){
        int h = (ct >> 4) & 7;
        #pragma unroll
        for (int r = 0; r < 8; r++){
            int row = row0 + rg * 8 + r;
            e1s[(size_t)row * HEADS + h] = ps[r];
            e1d[(size_t)row * HEADS + h] = pd[r];
        }
    }
}

// ---------------- layer 1 aggregation: one WAVE per node, no LDS, no barriers --

__global__ __launch_bounds__(256) void k_agg1(const float* __restrict__ h1,
                                              const float* __restrict__ e1s,
                                              const float* __restrict__ e1d,
                                              const int* __restrict__ offsets,
                                              const int* __restrict__ sortedSrc,
                                              const float* __restrict__ b1,
                                              float* __restrict__ hmid){
    const int lane = threadIdx.x & 63;
    const int d = blockIdx.x * 4 + (threadIdx.x >> 6);
    if (d >= N_NODES) return;
    const int beg = offsets[d], end = offsets[d + 1];
    const int cnt = end - beg;
    const int h = lane >> 3;
    const int c0 = lane * 8;
    const float ed = e1d[(size_t)d * HEADS + h];

    float4 acc0 = make_float4(0.f,0.f,0.f,0.f), acc1 = make_float4(0.f,0.f,0.f,0.f);
    float z = 0.f;

    int s1 = 0, s2 = 0;
    float eA = 0.f; float4 hA0, hA1;
    {   // prologue: loads for edge 0, src for edge 1
        int s0 = sortedSrc[beg];
        eA = e1s[(size_t)s0 * HEADS + h];
        const float4* hp = (const float4*)(h1 + (size_t)s0 * HC + c0);
        hA0 = hp[0]; hA1 = hp[1];
        if (cnt > 1) s1 = sortedSrc[beg + 1];
    }
    for (int e = 0; e < cnt; ++e){
        if (e + 2 < cnt) s2 = sortedSrc[beg + e + 2];
        float eB = 0.f; float4 hB0, hB1;
        if (e + 1 < cnt){
            eB = e1s[(size_t)s1 * HEADS + h];
            const float4* hp = (const float4*)(h1 + (size_t)s1 * HC + c0);
            hB0 = hp[0]; hB1 = hp[1];
        }
        float w = __expf(leaky(eA + ed));
        z += w;
        acc0.x = fmaf(w, hA0.x, acc0.x); acc0.y = fmaf(w, hA0.y, acc0.y);
        acc0.z = fmaf(w, hA0.z, acc0.z); acc0.w = fmaf(w, hA0.w, acc0.w);
        acc1.x = fmaf(w, hA1.x, acc1.x); acc1.y = fmaf(w, hA1.y, acc1.y);
        acc1.z = fmaf(w, hA1.z, acc1.z); acc1.w = fmaf(w, hA1.w, acc1.w);
        eA = eB; hA0 = hB0; hA1 = hB1; s1 = s2;
    }

    const float inv = 1.f / (z + 1e-16f);
    const float4 bv0 = ((const float4*)b1)[lane * 2];
    const float4 bv1 = ((const float4*)b1)[lane * 2 + 1];
    float4 o0, o1;
    o0.x = fmaxf(fmaf(acc0.x, inv, bv0.x), 0.f);
    o0.y = fmaxf(fmaf(acc0.y, inv, bv0.y), 0.f);
    o0.z = fmaxf(fmaf(acc0.z, inv, bv0.z), 0.f);
    o0.w = fmaxf(fmaf(acc0.w, inv, bv0.w), 0.f);
    o1.x = fmaxf(fmaf(acc1.x, inv, bv1.x), 0.f);
    o1.y = fmaxf(fmaf(acc1.y, inv, bv1.y), 0.f);
    o1.z = fmaxf(fmaf(acc1.z, inv, bv1.z), 0.f);
    o1.w = fmaxf(fmaf(acc1.w, inv, bv1.w), 0.f);
    float4* op = (float4*)(hmid + (size_t)d * HC + c0);
    op[0] = o0; op[1] = o1;
}

// ---------------- layer 2: GEMM + fused e2 ----------------
// hmid[50000,512] @ W2[512,40] -> h2. BM=128, BK=32, thread = 4 rows x 5 cols.
// All 64 lanes active; float2 LDS reads; pad-34 strides (conflict-free-ish).

__global__ __launch_bounds__(256) void k_gemm2e2(const float* __restrict__ hmid,
                                                 const float* __restrict__ W2,
                                                 const float* __restrict__ a2s,
                                                 const float* __restrict__ a2d,
                                                 float* __restrict__ h2,
                                                 float* __restrict__ e2s,
                                                 float* __restrict__ e2d){
    __shared__ float hs[128][34];
    __shared__ float ws[OUT_DIM][34];    // transposed: [col][k]
    const int t = threadIdx.x;
    const int row0 = blockIdx.x * 128;
    const int tc = t & 7;        // col group: cols tc*5 .. tc*5+4
    const int tr = t >> 3;       // row group: rows tr*4 .. tr*4+3

    float acc[4][5];
    #pragma unroll
    for (int i = 0; i < 4; i++)
        #pragma unroll
        for (int j = 0; j < 5; j++) acc[i][j] = 0.f;

    for (int kb = 0; kb < HC; kb += 32){
        // stage hmid tile: 128 rows x 32 k (float4 loads, float2 LDS writes)
        #pragma unroll
        for (int p = 0; p < 4; p++){
            int q = t + 256 * p;
            int r = q >> 3, k4 = (q & 7) * 4;
            int gr = row0 + r;
            float4 v = (gr < N_NODES) ? *(const float4*)&hmid[(size_t)gr * HC + kb + k4]
                                      : make_float4(0.f, 0.f, 0.f, 0.f);
            *(float2*)&hs[r][k4]     = make_float2(v.x, v.y);
            *(float2*)&hs[r][k4 + 2] = make_float2(v.z, v.w);
        }
        // stage W2 chunk transposed (coalesced global reads)
        for (int i = t; i < 32 * OUT_DIM; i += 256){
            int k = i / OUT_DIM, j = i - k * OUT_DIM;
            ws[j][k] = W2[(size_t)(kb + k) * OUT_DIM + j];
        }
        __syncthreads();
        #pragma unroll
        for (int k = 0; k < 32; k += 2){
            float2 hv[4], wv[5];
            #pragma unroll
            for (int i = 0; i < 4; i++) hv[i] = *(const float2*)&hs[tr * 4 + i][k];
            #pragma unroll
            for (int j = 0; j < 5; j++) wv[j] = *(const float2*)&ws[tc * 5 + j][k];
            #pragma unroll
            for (int i = 0; i < 4; i++)
                #pragma unroll
                for (int j = 0; j < 5; j++){
                    acc[i][j] = fmaf(hv[i].x, wv[j].x, acc[i][j]);
                    acc[i][j] = fmaf(hv[i].y, wv[j].y, acc[i][j]);
                }
        }
        __syncthreads();
    }

    // epilogue: store h2 + fused e2s/e2d (reduce over 8 col-groups = lanes tc)
    float as[5], ad[5];
    #pragma unroll
    for (int j = 0; j < 5; j++){ as[j] = a2s[tc * 5 + j]; ad[j] = a2d[tc * 5 + j]; }
    #pragma unroll
    for (int i = 0; i < 4; i++){
        int r = row0 + tr * 4 + i;
        bool ok = (r < N_NODES);
        float pvs = 0.f, pvd = 0.f;
        #pragma unroll
        for (int j = 0; j < 5; j++){
            if (ok) h2[(size_t)r * OUT_DIM + tc * 5 + j] = acc[i][j];
            pvs = fmaf(acc[i][j], as[j], pvs);
            pvd = fmaf(acc[i][j], ad[j], pvd);
        }
        pvs += __shfl_xor(pvs, 1, 64); pvd += __shfl_xor(pvd, 1, 64);
        pvs += __shfl_xor(pvs, 2, 64); pvd += __shfl_xor(pvd, 2, 64);
        pvs += __shfl_xor(pvs, 4, 64); pvd += __shfl_xor(pvd, 4, 64);
        if (tc == 0 && ok){ e2s[r] = pvs; e2d[r] = pvd; }
    }
}

// ---------------- layer 2 aggregation: one WAVE per node, pipelined ------------

__global__ __launch_bounds__(256) void k_agg2(const float* __restrict__ h2,
                                              const float* __restrict__ e2s,
                                              const float* __restrict__ e2d,
                                              const int* __restrict__ offsets,
                                              const int* __restrict__ sortedSrc,
                                              const float* __restrict__ b2,
                                              float* __restrict__ out){
    const int lane = threadIdx.x & 63;
    const int d = blockIdx.x * 4 + (threadIdx.x >> 6);
    if (d >= N_NODES) return;
    const int beg = offsets[d], end = offsets[d + 1];
    const int cnt = end - beg;
    const float ed = e2d[d];
    const bool act = (lane < OUT_DIM);

    float acc = 0.f, z = 0.f;
    int s1 = 0, s2 = 0;
    float eA = 0.f, hA = 0.f;
    {
        int s0 = sortedSrc[beg];
        eA = e2s[s0];
        if (act) hA = h2[(size_t)s0 * OUT_DIM + lane];
        if (cnt > 1) s1 = sortedSrc[beg + 1];
    }
    for (int e = 0; e < cnt; ++e){
        if (e + 2 < cnt) s2 = sortedSrc[beg + e + 2];
        float eB = 0.f, hB = 0.f;
        if (e + 1 < cnt){
            eB = e2s[s1];
            if (act) hB = h2[(size_t)s1 * OUT_DIM + lane];
        }
        float w = __expf(leaky(eA + ed));
        z += w;
        acc = fmaf(w, hA, acc);
        eA = eB; hA = hB; s1 = s2;
    }

    float o = acc / (z + 1e-16f) + (act ? b2[lane] : 0.f);
    float ov = act ? o : -INFINITY;
    float vmax = ov;
    #pragma unroll
    for (int off = 32; off > 0; off >>= 1) vmax = fmaxf(vmax, __shfl_xor(vmax, off, 64));
    float se = act ? __expf(o - vmax) : 0.f;
    #pragma unroll
    for (int off = 32; off > 0; off >>= 1) se += __shfl_xor(se, off, 64);
    if (act) out[(size_t)d * OUT_DIM + lane] = o - vmax - __logf(se);
}

// ---------------- launch ----------------

extern "C" void kernel_launch(void* const* d_in, const int* in_sizes, int n_in,
                              void* d_out, int out_size, void* d_ws, size_t ws_size,
                              hipStream_t stream){
    const float* x   = (const float*)d_in[0];
    const int*   ei  = (const int*)  d_in[1];
    const float* W1  = (const float*)d_in[2];
    const float* a1s = (const float*)d_in[3];
    const float* a1d = (const float*)d_in[4];
    const float* b1  = (const float*)d_in[5];
    const float* W2  = (const float*)d_in[6];
    const float* a2s = (const float*)d_in[7];
    const float* a2d = (const float*)d_in[8];
    const float* b2  = (const float*)d_in[9];
    float* out = (float*)d_out;

    char* ws = (char*)d_ws;
    size_t off = 0;
    auto alloc = [&](size_t bytes) -> char* {
        off = (off + 255) & ~(size_t)255;
        char* p = ws + off;
        off += bytes;
        return p;
    };

    float* h1      = (float*)alloc((size_t)N_NODES * HC * 4);
    float* hmid    = (float*)alloc((size_t)N_NODES * HC * 4);
    float* h2      = (float*)alloc((size_t)N_NODES * OUT_DIM * 4);
    float* e1s     = (float*)alloc((size_t)N_NODES * HEADS * 4);
    float* e1d     = (float*)alloc((size_t)N_NODES * HEADS * 4);
    float* e2s     = (float*)alloc((size_t)N_NODES * 4);
    float* e2d     = (float*)alloc((size_t)N_NODES * 4);
    int* counts    = (int*)alloc((size_t)N_NODES * 4);
    int* offsets   = (int*)alloc((size_t)(N_NODES + 1) * 4);
    int* cursor    = (int*)alloc((size_t)N_NODES * 4);
    int* blockSums = (int*)alloc(64 * 4);
    int* sortedSrc = (int*)alloc((size_t)E_TOT * 4);

    const int nb = (N_NODES + 1023) / 1024;  // 49

    hipMemsetAsync(counts, 0, (size_t)N_NODES * 4, stream);
    k_hist   <<<(E_TOT + 255) / 256, 256, 0, stream>>>(ei, counts);
    k_scanA  <<<nb, 1024, 0, stream>>>(counts, offsets, blockSums);
    k_scanB  <<<1, 64, 0, stream>>>(blockSums, nb);
    k_scanC  <<<nb, 1024, 0, stream>>>(counts, offsets, blockSums, cursor);
    k_scatter<<<(E_TOT + 255) / 256, 256, 0, stream>>>(ei, cursor, sortedSrc);

    k_gemm1e1<<<N_NODES / 16, 256, 0, stream>>>(x, W1, a1s, a1d, h1, e1s, e1d);
    k_agg1   <<<(N_NODES + 3) / 4, 256, 0, stream>>>(h1, e1s, e1d, offsets, sortedSrc, b1, hmid);

    k_gemm2e2<<<(N_NODES + 127) / 128, 256, 0, stream>>>(hmid, W2, a2s, a2d, h2, e2s, e2d);
    k_agg2   <<<(N_NODES + 3) / 4, 256, 0, stream>>>(h2, e2s, e2d, offsets, sortedSrc, b2, out);
}